// Round 5
// baseline (585.348 us; speedup 1.0000x reference)
//
#include <hip/hip_runtime.h>
#include <hip/hip_bf16.h>
#include <math.h>

#define B 8
#define L 4096
#define D 2048
#define H 16
#define HD 128
#define SCALE 0.08838834764831845f   // 1/sqrt(128)

#define KS1 32            // split-K factor for QKV GEMV
#define KC1 (D / KS1)     // 64 rows per chunk
#define KS2 32            // split-K factor for Wo GEMV
#define KC2 (D / KS2)
#define NCHUNK 8          // flash-decoding chunks over L
#define CLEN (L / NCHUNK) // 512

// ---------------- Kernel 1: QKV projections, split-K partials ----------------
// grid (D/1024, KS1, 3), block 256. Each thread owns 4 output cols (float4),
// accumulates all 8 batch rows so each weight element is read exactly once.
__global__ void qkv_partial(const float* __restrict__ x,
                            const float* __restrict__ Wq,
                            const float* __restrict__ Wk,
                            const float* __restrict__ Wv,
                            float* __restrict__ part) {
    const int m = blockIdx.z;
    const float* __restrict__ W = (m == 0) ? Wq : ((m == 1) ? Wk : Wv);
    const int kc = blockIdx.y;
    const int i0 = kc * KC1;
    const int col4 = (blockIdx.x * 256 + threadIdx.x) * 4;

    __shared__ __align__(16) float xs[KC1][8];   // [row-in-chunk][batch]
    for (int t = threadIdx.x; t < KC1 * 8; t += 256) {
        int ii = t >> 3, b = t & 7;
        xs[ii][b] = x[b * D + i0 + ii];
    }
    __syncthreads();

    float4 acc[8];
#pragma unroll
    for (int b = 0; b < 8; b++) acc[b] = make_float4(0.f, 0.f, 0.f, 0.f);

    for (int ii = 0; ii < KC1; ii++) {
        float4 w = *reinterpret_cast<const float4*>(&W[(size_t)(i0 + ii) * D + col4]);
        float4 xa = *reinterpret_cast<const float4*>(&xs[ii][0]);
        float4 xb = *reinterpret_cast<const float4*>(&xs[ii][4]);
        float xv[8] = {xa.x, xa.y, xa.z, xa.w, xb.x, xb.y, xb.z, xb.w};
#pragma unroll
        for (int b = 0; b < 8; b++) {
            acc[b].x += xv[b] * w.x;
            acc[b].y += xv[b] * w.y;
            acc[b].z += xv[b] * w.z;
            acc[b].w += xv[b] * w.w;
        }
    }
#pragma unroll
    for (int b = 0; b < 8; b++) {
        *reinterpret_cast<float4*>(&part[(((size_t)m * KS1 + kc) * B + b) * D + col4]) = acc[b];
    }
}

// ------------- Kernel 2: reduce split-K partials + RoPE on q,k ---------------
// grid (D/256, B, 3), block 256.
__global__ void qkv_reduce_rope(const float* __restrict__ part,
                                const int* __restrict__ cache_len,
                                float* __restrict__ qkv) {
    const int m = blockIdx.z, b = blockIdx.y;
    const int col = blockIdx.x * 256 + threadIdx.x;
    float s = 0.f;
    for (int kc = 0; kc < KS1; kc++)
        s += part[(((size_t)m * KS1 + kc) * B + b) * D + col];

    __shared__ float sums[256];
    sums[threadIdx.x] = s;
    __syncthreads();

    float val;
    if (m < 2) {  // q or k: RoPE with pos = cache_len (S==1)
        const int hd = col & (HD - 1);   // col tile is 256 = 2 heads, pairs stay in-block
        const int f = hd & 63;
        double inv = pow(10000.0, -(double)f / 64.0);
        double ang = (double)(*cache_len) * inv;
        float c = (float)cos(ang), sn = (float)sin(ang);
        if (hd < 64) val = sums[threadIdx.x] * c - sums[threadIdx.x + 64] * sn;
        else         val = sums[threadIdx.x - 64] * sn + sums[threadIdx.x] * c;
    } else {
        val = s;
    }
    qkv[((size_t)m * B + b) * D + col] = val;
}

// -------- Kernel 3: flash-decoding partial attention over an L-chunk ---------
// grid (NCHUNK, H, B), block 256 = 8 groups of 32 lanes; each group handles one
// key position per iteration (float4 per lane covers HD=128).
__global__ void attn_partial(const float* __restrict__ k_cache,
                             const float* __restrict__ v_cache,
                             const float* __restrict__ qkv,
                             float* __restrict__ part) {
    const int chunk = blockIdx.x, h = blockIdx.y, b = blockIdx.z;
    const int tid = threadIdx.x;
    const int g = tid >> 5, lane = tid & 31;

    __shared__ __align__(16) float qs[HD];
    __shared__ __align__(16) float og[8][HD];
    __shared__ float gm[8], gl[8];

    if (tid < HD) qs[tid] = qkv[(size_t)b * D + h * HD + tid];  // q (m=0)
    __syncthreads();
    const float4 q4 = reinterpret_cast<const float4*>(qs)[lane];

    const float* __restrict__ kb = k_cache + (size_t)b * L * D + h * HD;  // H*HD == D
    const float* __restrict__ vb = v_cache + (size_t)b * L * D + h * HD;

    float m_run = -1e30f, l_run = 0.f;
    float4 o4 = make_float4(0.f, 0.f, 0.f, 0.f);
    const int l0 = chunk * CLEN;

    for (int it = 0; it < CLEN / 8; it++) {
        const int l = l0 + it * 8 + g;
        float4 k4 = *reinterpret_cast<const float4*>(kb + (size_t)l * D + lane * 4);
        float4 v4 = *reinterpret_cast<const float4*>(vb + (size_t)l * D + lane * 4);
        float dot = k4.x * q4.x + k4.y * q4.y + k4.z * q4.z + k4.w * q4.w;
#pragma unroll
        for (int off = 16; off >= 1; off >>= 1) dot += __shfl_xor(dot, off);
        const float sc = dot * SCALE;
        const float mn = fmaxf(m_run, sc);
        const float r = expf(m_run - mn);
        const float p = expf(sc - mn);
        l_run = l_run * r + p;
        o4.x = o4.x * r + p * v4.x;
        o4.y = o4.y * r + p * v4.y;
        o4.z = o4.z * r + p * v4.z;
        o4.w = o4.w * r + p * v4.w;
        m_run = mn;
    }

    // last chunk also takes the freshly-projected (RoPE'd) token at pos L
    if (chunk == NCHUNK - 1 && g == 0) {
        const float* kn = qkv + ((size_t)1 * B + b) * D + h * HD;
        const float* vn = qkv + ((size_t)2 * B + b) * D + h * HD;
        float4 k4 = *reinterpret_cast<const float4*>(kn + lane * 4);
        float4 v4 = *reinterpret_cast<const float4*>(vn + lane * 4);
        float dot = k4.x * q4.x + k4.y * q4.y + k4.z * q4.z + k4.w * q4.w;
#pragma unroll
        for (int off = 16; off >= 1; off >>= 1) dot += __shfl_xor(dot, off);
        const float sc = dot * SCALE;
        const float mn = fmaxf(m_run, sc);
        const float r = expf(m_run - mn);
        const float p = expf(sc - mn);
        l_run = l_run * r + p;
        o4.x = o4.x * r + p * v4.x;
        o4.y = o4.y * r + p * v4.y;
        o4.z = o4.z * r + p * v4.z;
        o4.w = o4.w * r + p * v4.w;
        m_run = mn;
    }

    reinterpret_cast<float4*>(&og[g][0])[lane] = o4;
    if (lane == 0) { gm[g] = m_run; gl[g] = l_run; }
    __syncthreads();

    float M = gm[0];
#pragma unroll
    for (int i = 1; i < 8; i++) M = fmaxf(M, gm[i]);

    float* outp = part + ((size_t)(b * H + h) * NCHUNK + chunk) * (HD + 2);
    if (tid < HD) {
        float o = 0.f;
#pragma unroll
        for (int i = 0; i < 8; i++) o += expf(gm[i] - M) * og[i][tid];
        outp[2 + tid] = o;
    } else if (tid == 128) {
        float S = 0.f;
#pragma unroll
        for (int i = 0; i < 8; i++) S += expf(gm[i] - M) * gl[i];
        outp[0] = M;
        outp[1] = S;
    }
}

// ---------------- Kernel 4: combine chunk partials per (b,h) -----------------
// grid (B*H), block 128.
__global__ void attn_combine(const float* __restrict__ part,
                             float* __restrict__ attn_out) {
    const int bh = blockIdx.x;
    const int tid = threadIdx.x;
    const float* __restrict__ p = part + (size_t)bh * NCHUNK * (HD + 2);
    float M = -1e30f;
#pragma unroll
    for (int c = 0; c < NCHUNK; c++) M = fmaxf(M, p[c * (HD + 2)]);
    float S = 0.f, o = 0.f;
#pragma unroll
    for (int c = 0; c < NCHUNK; c++) {
        const float e = expf(p[c * (HD + 2)] - M);
        S += e * p[c * (HD + 2) + 1];
        o += e * p[c * (HD + 2) + 2 + tid];
    }
    attn_out[(size_t)(bh / H) * D + (bh % H) * HD + tid] = o / S;
}

// ---------------- Kernel 5: output projection, split-K partials --------------
// grid (D/1024, KS2), block 256.
__global__ void o_partial(const float* __restrict__ xin,
                          const float* __restrict__ Wo,
                          float* __restrict__ part) {
    const int kc = blockIdx.y;
    const int i0 = kc * KC2;
    const int col4 = (blockIdx.x * 256 + threadIdx.x) * 4;

    __shared__ __align__(16) float xs[KC2][8];
    for (int t = threadIdx.x; t < KC2 * 8; t += 256) {
        int ii = t >> 3, b = t & 7;
        xs[ii][b] = xin[b * D + i0 + ii];
    }
    __syncthreads();

    float4 acc[8];
#pragma unroll
    for (int b = 0; b < 8; b++) acc[b] = make_float4(0.f, 0.f, 0.f, 0.f);

    for (int ii = 0; ii < KC2; ii++) {
        float4 w = *reinterpret_cast<const float4*>(&Wo[(size_t)(i0 + ii) * D + col4]);
        float4 xa = *reinterpret_cast<const float4*>(&xs[ii][0]);
        float4 xb = *reinterpret_cast<const float4*>(&xs[ii][4]);
        float xv[8] = {xa.x, xa.y, xa.z, xa.w, xb.x, xb.y, xb.z, xb.w};
#pragma unroll
        for (int b = 0; b < 8; b++) {
            acc[b].x += xv[b] * w.x;
            acc[b].y += xv[b] * w.y;
            acc[b].z += xv[b] * w.z;
            acc[b].w += xv[b] * w.w;
        }
    }
#pragma unroll
    for (int b = 0; b < 8; b++) {
        *reinterpret_cast<float4*>(&part[(((size_t)kc) * B + b) * D + col4]) = acc[b];
    }
}

// ---------------- Kernel 6: reduce Wo split-K partials → d_out ---------------
// grid (D/256, B), block 256.
__global__ void o_reduce(const float* __restrict__ part,
                         float* __restrict__ out) {
    const int b = blockIdx.y;
    const int col = blockIdx.x * 256 + threadIdx.x;
    float s = 0.f;
    for (int kc = 0; kc < KS2; kc++)
        s += part[((size_t)kc * B + b) * D + col];
    out[(size_t)b * D + col] = s;
}

extern "C" void kernel_launch(void* const* d_in, const int* in_sizes, int n_in,
                              void* d_out, int out_size, void* d_ws, size_t ws_size,
                              hipStream_t stream) {
    const float* x       = (const float*)d_in[0];
    const float* k_cache = (const float*)d_in[1];
    const float* v_cache = (const float*)d_in[2];
    const float* Wq      = (const float*)d_in[3];
    const float* Wk      = (const float*)d_in[4];
    const float* Wv      = (const float*)d_in[5];
    const float* Wo      = (const float*)d_in[6];
    const int*   cache_len = (const int*)d_in[7];
    float* out = (float*)d_out;

    float* ws    = (float*)d_ws;
    float* qkvp  = ws;                                   // 3*KS1*B*D
    float* qkv   = qkvp  + (size_t)3 * KS1 * B * D;      // 3*B*D  (q,k,v after RoPE)
    float* attnp = qkv   + (size_t)3 * B * D;            // B*H*NCHUNK*(HD+2)
    float* attno = attnp + (size_t)B * H * NCHUNK * (HD + 2); // B*D
    float* op    = attno + (size_t)B * D;                // KS2*B*D

    qkv_partial<<<dim3(D / 1024, KS1, 3), 256, 0, stream>>>(x, Wq, Wk, Wv, qkvp);
    qkv_reduce_rope<<<dim3(D / 256, B, 3), 256, 0, stream>>>(qkvp, cache_len, qkv);
    attn_partial<<<dim3(NCHUNK, H, B), 256, 0, stream>>>(k_cache, v_cache, qkv, attnp);
    attn_combine<<<dim3(B * H), 128, 0, stream>>>(attnp, attno);
    o_partial<<<dim3(D / 1024, KS2), 256, 0, stream>>>(attno, Wo, op);
    o_reduce<<<dim3(D / 256, B), 256, 0, stream>>>(op, out);
}